// Round 1
// baseline (2184.035 us; speedup 1.0000x reference)
//
#include <hip/hip_runtime.h>
#include <hip/hip_bf16.h>
#include <cstdint>

// ---------------- prep1: s_feat (RMS-normalized), wnscale, rgb coefs ----------------
__global__ __launch_bounds__(256) void prep1_kernel(
    const float* __restrict__ w,        // (2,512)
    const float* __restrict__ afw,      // (128,512)
    const float* __restrict__ afb,      // (128)
    const float* __restrict__ argbw,    // (128,512)
    const float* __restrict__ argbb,    // (128)
    const float* __restrict__ wrgb,     // (3,128)
    const float* __restrict__ wfeat,    // (128,128,3,3)
    const float* __restrict__ ema_r,    // (1)
    float* __restrict__ s_feat_out,     // (2,128)
    float* __restrict__ wnscale_out,    // (128)
    float* __restrict__ coef_out)       // (2,3,128)
{
  __shared__ float sred[256];
  __shared__ float srgb_l[256];
  const int tid = threadIdx.x;
  const int b = tid >> 7, c = tid & 127;
  const float wg = 0.04419417382415922f;    // 1/sqrt(512)
  float d1 = 0.f, d2 = 0.f;
  for (int k = 0; k < 512; ++k) {
    float wv = w[b*512 + k];
    d1 += wv * afw[c*512 + k];
    d2 += wv * argbw[c*512 + k];
  }
  float sfeat = d1 * wg + afb[c];
  float srgb  = (d2 * wg + argbb[c]) * 0.08838834764831845f /*1/sqrt(128)*/ * rsqrtf(ema_r[0]);
  sred[tid] = sfeat * sfeat;
  srgb_l[tid] = srgb;
  __syncthreads();
  for (int off = 128; off > 0; off >>= 1) {
    if (tid < off) sred[tid] += sred[tid + off];
    __syncthreads();
  }
  const float snorm = rsqrtf(sred[0] * (1.0f/256.0f));
  s_feat_out[tid] = sfeat * snorm;
  if (tid < 128) {
    float ss = 0.f;
    for (int e = 0; e < 1152; ++e) { float v = wfeat[tid*1152 + e]; ss += v*v; }
    wnscale_out[tid] = rsqrtf(ss * (1.0f/1152.0f));
  }
  for (int e = tid; e < 768; e += 256) {
    int bb = e / 384, o = (e % 384) / 128, i = e & 127;
    coef_out[e] = wrgb[o*128 + i] * srgb_l[bb*128 + i];
  }
}

// ---------------- prep2: modulated + demodulated weights, layout [b][i][kk][o] ----------------
__global__ __launch_bounds__(128) void prep2_kernel(
    const float* __restrict__ wfeat, const float* __restrict__ s_feat,
    const float* __restrict__ wnscale, const float* __restrict__ ema_f,
    float* __restrict__ wmod)
{
  __shared__ float red[128];
  const int bo = blockIdx.x, b = bo >> 7, o = bo & 127;
  const int i = threadIdx.x;
  const float wsc = wnscale[o];
  const float sv = s_feat[b*128 + i];
  float wr[9]; float ss = 0.f;
  #pragma unroll
  for (int j = 0; j < 9; ++j) { wr[j] = wfeat[(o*128 + i)*9 + j] * wsc * sv; ss += wr[j]*wr[j]; }
  red[i] = ss; __syncthreads();
  for (int off = 64; off > 0; off >>= 1) { if (i < off) red[i] += red[i+off]; __syncthreads(); }
  const float d = rsqrtf(red[0] + 1e-8f) * rsqrtf(ema_f[0]);
  #pragma unroll
  for (int j = 0; j < 9; ++j) wmod[((b*128 + i)*9 + j)*128 + o] = wr[j] * d;
}

// ---------------- conv: 3x3, pad 2, (2,128,256,256)->(2,128,258,258), +bias ----------------
// block: 32 o-channels x 16x16 spatial tile; thread: 8 o x 2x2 spatial (32 acc)
__global__ __launch_bounds__(256) void conv_kernel(
    const float* __restrict__ x, const float* __restrict__ wmod,
    const float* __restrict__ bias_feat, float* __restrict__ conv_out)
{
  __shared__ float xs[4][18][20];
  __shared__ float wl[4][9][32];
  const int o0 = blockIdx.x * 32;
  const int ti = blockIdx.y;
  const int b = blockIdx.z;
  const int y0 = (ti / 17) * 16, x0 = (ti % 17) * 16;
  const int tid = threadIdx.x;
  const int og = tid >> 6, s = tid & 63, sy = s >> 3, sx = s & 7;

  float acc[2][2][8];
  #pragma unroll
  for (int a = 0; a < 2; ++a)
    #pragma unroll
    for (int bb = 0; bb < 2; ++bb)
      #pragma unroll
      for (int j = 0; j < 8; ++j) acc[a][bb][j] = 0.f;

  #pragma unroll 1
  for (int ic0 = 0; ic0 < 128; ic0 += 4) {
    __syncthreads();
    #pragma unroll 1
    for (int e = tid; e < 1296; e += 256) {
      int di = e / 324; int rem = e - di*324; int r = rem / 18, cc = rem - r*18;
      int gy = y0 - 2 + r, gx = x0 - 2 + cc;
      float v = 0.f;
      if ((unsigned)gy < 256u && (unsigned)gx < 256u)
        v = x[((b*128 + ic0 + di)*256 + gy)*256 + gx];
      xs[di][r][cc] = v;
    }
    #pragma unroll 1
    for (int e = tid; e < 1152; e += 256) {
      int di = e / 288; int rem = e - di*288; int kk = rem >> 5, o = rem & 31;
      wl[di][kk][o] = wmod[((b*128 + ic0 + di)*9 + kk)*128 + o0 + o];
    }
    __syncthreads();
    #pragma unroll
    for (int di = 0; di < 4; ++di) {
      #pragma unroll
      for (int ky = 0; ky < 3; ++ky) {
        const int r0 = 2*sy + ky;
        float xv0[4], xv1[4];
        *(float2*)&xv0[0] = *(const float2*)&xs[di][r0][2*sx];
        *(float2*)&xv0[2] = *(const float2*)&xs[di][r0][2*sx+2];
        *(float2*)&xv1[0] = *(const float2*)&xs[di][r0+1][2*sx];
        *(float2*)&xv1[2] = *(const float2*)&xs[di][r0+1][2*sx+2];
        float wv[3][8];
        #pragma unroll
        for (int kx = 0; kx < 3; ++kx) {
          *(float4*)&wv[kx][0] = *(const float4*)&wl[di][3*ky+kx][og*8];
          *(float4*)&wv[kx][4] = *(const float4*)&wl[di][3*ky+kx][og*8+4];
        }
        #pragma unroll
        for (int j = 0; j < 8; ++j) {
          acc[0][0][j] += xv0[0]*wv[0][j] + xv0[1]*wv[1][j] + xv0[2]*wv[2][j];
          acc[0][1][j] += xv0[1]*wv[0][j] + xv0[2]*wv[1][j] + xv0[3]*wv[2][j];
          acc[1][0][j] += xv1[0]*wv[0][j] + xv1[1]*wv[1][j] + xv1[2]*wv[2][j];
          acc[1][1][j] += xv1[1]*wv[0][j] + xv1[2]*wv[1][j] + xv1[3]*wv[2][j];
        }
      }
    }
  }
  #pragma unroll
  for (int j = 0; j < 8; ++j) {
    const int oc = o0 + og*8 + j;
    const float bz = bias_feat[oc];
    #pragma unroll
    for (int py = 0; py < 2; ++py)
      #pragma unroll
      for (int px = 0; px < 2; ++px) {
        int n = y0 + 2*sy + py, m = x0 + 2*sx + px;
        if (n < 258 && m < 258)
          conv_out[((b*128 + oc)*258 + n)*258 + m] = acc[py][px][j] + bz;
      }
  }
}

// ---------------- fused up2x (sep) + lrelu/clamp + down2x (sep) ----------------
// grid (32 y-strips, 128 c, 2 b); strip = 8 output rows, full width.
__global__ __launch_bounds__(256) void updown_kernel(
    const float* __restrict__ conv_out,
    const float* __restrict__ upf, const float* __restrict__ dnf,
    float* __restrict__ down2)
{
  __shared__ float Bp[26][266];   // up1 strip, 4-col zero pad each side (cols m+4)
  __shared__ float Dp[8][523];    // down1 strip (522 cols, +1 pad)
  const int strip = blockIdx.x, c = blockIdx.y, b = blockIdx.z;
  const int y0 = strip * 8;
  const int tid = threadIdx.x;
  float fu[12], fd[12];
  #pragma unroll
  for (int k = 0; k < 12; ++k) { fu[k] = upf[11-k] * 2.0f; fd[k] = dnf[11-k]; }
  if (tid < 208) { int r = tid >> 3, pc = tid & 7; int col = (pc < 4) ? pc : (258 + pc); Bp[r][col] = 0.f; }
  const float* src = conv_out + ((b*128 + c)*258)*258;

  // P1: vertical upsample, global -> LDS (threads over columns m)
  #pragma unroll 1
  for (int m = tid; m < 258; m += 256) {
    float a[18];
    #pragma unroll
    for (int r = 0; r < 18; ++r) {
      int gy = y0 - 4 + r;
      a[r] = ((unsigned)gy < 258u) ? src[gy*258 + m] : 0.f;
    }
    #pragma unroll
    for (int v = 0; v < 26; ++v) {
      const int k0 = (v & 1) ? 0 : 1;        // global row parity == v parity
      float sacc = 0.f;
      #pragma unroll
      for (int j = 0; j < 6; ++j) {
        const int rl = (v + k0 + 2*j - 9)/2 + 4;   // compile-time, in [0,25]... bounded [0,25]
        sacc += fu[k0 + 2*j] * a[rl];
      }
      Bp[v][m + 4] = sacc;
    }
  }
  __syncthreads();

  // P2: horizontal upsample + lrelu + vertical downsample (threads over u-pairs q)
  #pragma unroll 1
  for (int q = tid; q < 261; q += 256) {
    float dacc0[8], dacc1[8];
    #pragma unroll
    for (int t = 0; t < 8; ++t) { dacc0[t] = 0.f; dacc1[t] = 0.f; }
    #pragma unroll
    for (int v = 0; v < 26; ++v) {
      float w0 = Bp[v][q+0], w1 = Bp[v][q+1], w2 = Bp[v][q+2];
      float w3 = Bp[v][q+3], w4 = Bp[v][q+4], w5 = Bp[v][q+5];
      float c0 = fu[1]*w0 + fu[3]*w1 + fu[5]*w2 + fu[7]*w3 + fu[9]*w4 + fu[11]*w5; // u=2q
      float c1 = fu[0]*w0 + fu[2]*w1 + fu[4]*w2 + fu[6]*w3 + fu[8]*w4 + fu[10]*w5; // u=2q+1
      c0 = fminf(fmaxf((c0 < 0.f ? c0*0.2f : c0)*1.41421356237f, -256.f), 256.f);
      c1 = fminf(fmaxf((c1 < 0.f ? c1*0.2f : c1)*1.41421356237f, -256.f), 256.f);
      #pragma unroll
      for (int t = 0; t < 8; ++t) {
        const int k = v - 2*t;
        if (k >= 0 && k < 12) { dacc0[t] += fd[k]*c0; dacc1[t] += fd[k]*c1; }
      }
    }
    #pragma unroll
    for (int t = 0; t < 8; ++t) { Dp[t][2*q] = dacc0[t]; Dp[t][2*q+1] = dacc1[t]; }
  }
  __syncthreads();

  // P3: horizontal downsample, LDS -> global (ty rows x strided cols; coalesced stores)
  const int ty = tid >> 5, xg = tid & 31;
  float* dst = down2 + ((b*128 + c)*256 + (y0 + ty))*256;
  #pragma unroll
  for (int i = 0; i < 8; ++i) {
    int xc = xg + 32*i;
    float acc = 0.f;
    #pragma unroll
    for (int k = 0; k < 12; ++k) acc += fd[k] * Dp[ty][2*xc + k];
    dst[xc] = acc;
  }
}

// ---------------- rgb: y[b,o,p] = clamp(sum_i coef[b,o,i]*down2[b,i,p] + bias, +-256) ----------------
__global__ __launch_bounds__(256) void rgb_kernel(
    const float* __restrict__ down2, const float* __restrict__ coef,
    const float* __restrict__ brgb, float* __restrict__ yout)
{
  __shared__ float cl[3][128];
  const int b = blockIdx.x >> 8;
  const int p = ((blockIdx.x & 255) << 8) + threadIdx.x;
  for (int e = threadIdx.x; e < 384; e += 256) cl[e >> 7][e & 127] = coef[b*384 + e];
  __syncthreads();
  float a0 = 0.f, a1 = 0.f, a2 = 0.f;
  const float* dsrc = down2 + (size_t)b*128*65536 + p;
  #pragma unroll 4
  for (int i = 0; i < 128; ++i) {
    float v = dsrc[(size_t)i*65536];
    a0 += cl[0][i]*v; a1 += cl[1][i]*v; a2 += cl[2][i]*v;
  }
  const size_t ob = (size_t)b*3*65536 + p;
  yout[ob]          = fminf(fmaxf(a0 + brgb[0], -256.f), 256.f);
  yout[ob + 65536]  = fminf(fmaxf(a1 + brgb[1], -256.f), 256.f);
  yout[ob + 131072] = fminf(fmaxf(a2 + brgb[2], -256.f), 256.f);
}

extern "C" void kernel_launch(void* const* d_in, const int* in_sizes, int n_in,
                              void* d_out, int out_size, void* d_ws, size_t ws_size,
                              hipStream_t stream) {
  const float* x      = (const float*)d_in[0];
  const float* w      = (const float*)d_in[1];
  const float* afw    = (const float*)d_in[2];
  const float* afb    = (const float*)d_in[3];
  const float* wfeat  = (const float*)d_in[4];
  const float* bfeat  = (const float*)d_in[5];
  const float* argbw  = (const float*)d_in[6];
  const float* argbb  = (const float*)d_in[7];
  const float* wrgb   = (const float*)d_in[8];
  const float* brgb   = (const float*)d_in[9];
  const float* upf    = (const float*)d_in[10];
  const float* dnf    = (const float*)d_in[11];
  const float* emaf   = (const float*)d_in[12];
  const float* emar   = (const float*)d_in[13];

  float* ws = (float*)d_ws;
  size_t off = 0;
  float* s_feat   = ws + off; off += 256;
  float* wnscale  = ws + off; off += 128;
  float* coef     = ws + off; off += 768;
  float* wmod     = ws + off; off += 294912;                    // [2][128][9][128]
  float* conv_out = ws + off; off += (size_t)2*128*258*258;     // 17,040,384
  float* down2    = ws + off; off += (size_t)2*128*256*256;     // 16,777,216
  if (ws_size < off * sizeof(float)) return;                    // fail loudly (out stays poisoned)
  float* yout = (float*)d_out;

  prep1_kernel<<<1, 256, 0, stream>>>(w, afw, afb, argbw, argbb, wrgb, wfeat, emar,
                                      s_feat, wnscale, coef);
  prep2_kernel<<<256, 128, 0, stream>>>(wfeat, s_feat, wnscale, emaf, wmod);
  conv_kernel<<<dim3(4, 289, 2), 256, 0, stream>>>(x, wmod, bfeat, conv_out);
  updown_kernel<<<dim3(32, 128, 2), 256, 0, stream>>>(conv_out, upf, dnf, down2);
  rgb_kernel<<<512, 256, 0, stream>>>(down2, coef, brgb, yout);
}

// Round 2
// 339.077 us; speedup vs baseline: 6.4411x; 6.4411x over previous
//
#include <hip/hip_runtime.h>
#include <hip/hip_bf16.h>
#include <cstdint>

typedef __attribute__((ext_vector_type(8))) short bf16x8;
typedef __attribute__((ext_vector_type(4))) float f32x4;

__device__ inline uint16_t f2bf(float f) {
  uint32_t u = __float_as_uint(f);
  u += 0x7FFF + ((u >> 16) & 1);          // round-to-nearest-even
  return (uint16_t)(u >> 16);
}

// ---------------- prep1: s_feat (RMS-normalized), wnscale, rgb coefs ----------------
__global__ __launch_bounds__(256) void prep1_kernel(
    const float* __restrict__ w,        // (2,512)
    const float* __restrict__ afw,      // (128,512)
    const float* __restrict__ afb,      // (128)
    const float* __restrict__ argbw,    // (128,512)
    const float* __restrict__ argbb,    // (128)
    const float* __restrict__ wrgb,     // (3,128)
    const float* __restrict__ wfeat,    // (128,128,3,3)
    const float* __restrict__ ema_r,    // (1)
    float* __restrict__ s_feat_out,     // (2,128)
    float* __restrict__ wnscale_out,    // (128)
    float* __restrict__ coef_out)       // (2,3,128)
{
  __shared__ float sred[256];
  __shared__ float srgb_l[256];
  const int tid = threadIdx.x;
  const int b = tid >> 7, c = tid & 127;
  const float wg = 0.04419417382415922f;    // 1/sqrt(512)
  float d1 = 0.f, d2 = 0.f;
  for (int k = 0; k < 512; ++k) {
    float wv = w[b*512 + k];
    d1 += wv * afw[c*512 + k];
    d2 += wv * argbw[c*512 + k];
  }
  float sfeat = d1 * wg + afb[c];
  float srgb  = (d2 * wg + argbb[c]) * 0.08838834764831845f /*1/sqrt(128)*/ * rsqrtf(ema_r[0]);
  sred[tid] = sfeat * sfeat;
  srgb_l[tid] = srgb;
  __syncthreads();
  for (int off = 128; off > 0; off >>= 1) {
    if (tid < off) sred[tid] += sred[tid + off];
    __syncthreads();
  }
  const float snorm = rsqrtf(sred[0] * (1.0f/256.0f));
  s_feat_out[tid] = sfeat * snorm;
  if (tid < 128) {
    float ss = 0.f;
    for (int e = 0; e < 1152; ++e) { float v = wfeat[tid*1152 + e]; ss += v*v; }
    wnscale_out[tid] = rsqrtf(ss * (1.0f/1152.0f));
  }
  for (int e = tid; e < 768; e += 256) {
    int bb = e / 384, o = (e % 384) / 128, i = e & 127;
    coef_out[e] = wrgb[o*128 + i] * srgb_l[bb*128 + i];
  }
}

// ---------------- prep2: modulated+demodulated weights -> bf16 MFMA A-fragments ----------------
// wfrag layout: [b][kidx 0..35][mglob 0..7][lane 0..63][j 0..7]  (short/bf16)
// kidx = chunk*9 + tap; chunk = ic>>5; k-lane: ic_local = (lane>>4)*8 + j; row = oc&15 = lane&15
__global__ __launch_bounds__(128) void prep2_kernel(
    const float* __restrict__ wfeat, const float* __restrict__ s_feat,
    const float* __restrict__ wnscale, const float* __restrict__ ema_f,
    short* __restrict__ wfrag)
{
  __shared__ float red[128];
  const int bo = blockIdx.x, b = bo >> 7, o = bo & 127;
  const int i = threadIdx.x;
  const float wsc = wnscale[o];
  const float sv = s_feat[b*128 + i];
  float wr[9]; float ss = 0.f;
  #pragma unroll
  for (int j = 0; j < 9; ++j) { wr[j] = wfeat[(o*128 + i)*9 + j] * wsc * sv; ss += wr[j]*wr[j]; }
  red[i] = ss; __syncthreads();
  for (int off = 64; off > 0; off >>= 1) { if (i < off) red[i] += red[i+off]; __syncthreads(); }
  const float d = rsqrtf(red[0] + 1e-8f) * rsqrtf(ema_f[0]);
  const int chunk = i >> 5;
  const int lane = (o & 15) | (((i >> 3) & 3) << 4);
  const int jj = i & 7;
  #pragma unroll
  for (int tap = 0; tap < 9; ++tap) {
    int kidx = chunk*9 + tap;
    size_t sidx = ((((size_t)b*36 + kidx)*8 + (o >> 4)) << 9) + (lane << 3) + jj;
    wfrag[sidx] = (short)f2bf(wr[tap] * d);
  }
}

// ---------------- conv via bf16 MFMA implicit GEMM ----------------
// block: 128 oc x (4 rows x 32 cols) pixels; 4 waves 2x2; wave: 64 oc x 64 px
// x staged per 32-ic chunk: LDS [6][36][32ic] bf16, row-stride 80B, chunk-slot XOR swizzle
__global__ __launch_bounds__(256) void conv_mfma_kernel(
    const float* __restrict__ x, const short* __restrict__ wfrag,
    const float* __restrict__ bias_feat, float* __restrict__ conv_out)
{
  __shared__ char xs[17280];
  __shared__ float bias_lds[128];
  const int tid = threadIdx.x;
  const int bx = blockIdx.x, by = blockIdx.y, b = blockIdx.z;
  const int x0 = bx * 32, y0 = by * 4;
  const int lane = tid & 63, wave = tid >> 6;
  const int wm = wave >> 1, wn = wave & 1;
  const int l15 = lane & 15, lq = lane >> 4;
  if (tid < 128) bias_lds[tid] = bias_feat[tid];

  f32x4 acc[4][4] = {};

  // staging mapping: 8 ic-pairs x 32 cols
  const int pr = tid >> 5, cw = tid & 31;

  const short* wbase = wfrag + (((size_t)b*36*8) + (size_t)wm*4) * 512 + (size_t)lane * 8;

  bf16x8 af[4], afn[4];
  #pragma unroll
  for (int m = 0; m < 4; ++m) af[m] = *(const bf16x8*)(wbase + m*512);   // kidx 0

  #pragma unroll 1
  for (int ch = 0; ch < 4; ++ch) {
    __syncthreads();
    // ---- stage x chunk [ch*32, ch*32+32) ----
    #pragma unroll
    for (int s = 0; s < 2; ++s) {
      const int pp = pr + 8*s;                 // ic-pair index 0..15
      const int ic = ch*32 + 2*pp;
      const float* s0 = x + ((size_t)(b*128 + ic)) * 65536;
      const float* s1 = s0 + 65536;
      #pragma unroll
      for (int r = 0; r < 6; ++r) {
        const int gy = y0 - 2 + r;
        const bool yok = (unsigned)gy < 256u;
        const int gx = x0 - 2 + cw;
        float v0 = 0.f, v1 = 0.f;
        if (yok && (unsigned)gx < 256u) { v0 = s0[gy*256 + gx]; v1 = s1[gy*256 + gx]; }
        uint32_t pk = ((uint32_t)f2bf(v1) << 16) | f2bf(v0);
        *(uint32_t*)&xs[(r*36 + cw)*80 + (((pp>>2) ^ ((cw>>3)&3)) << 4) + ((pp&3) << 2)] = pk;
        if (cw < 2) {
          const int c2 = 32 + cw, gx2 = x0 + 30 + cw;
          float u0 = 0.f, u1 = 0.f;
          if (yok && (unsigned)gx2 < 256u) { u0 = s0[gy*256 + gx2]; u1 = s1[gy*256 + gx2]; }
          uint32_t pk2 = ((uint32_t)f2bf(u1) << 16) | f2bf(u0);
          *(uint32_t*)&xs[(r*36 + c2)*80 + (((pp>>2) ^ ((c2>>3)&3)) << 4) + ((pp&3) << 2)] = pk2;
        }
      }
    }
    __syncthreads();
    // ---- 9 taps over this chunk ----
    #pragma unroll
    for (int ky = 0; ky < 3; ++ky) {
      #pragma unroll
      for (int kx = 0; kx < 3; ++kx) {
        const int kidx = ch*9 + ky*3 + kx;
        if (kidx < 35) {                       // prefetch next kstep's A-frags
          const short* wp = wbase + (size_t)(kidx + 1) * 4096;
          #pragma unroll
          for (int m = 0; m < 4; ++m) afn[m] = *(const bf16x8*)(wp + m*512);
        }
        bf16x8 bfr[4];
        #pragma unroll
        for (int n = 0; n < 4; ++n) {
          const int r = wn*2 + (n>>1) + ky;
          const int c = (n&1)*16 + l15 + kx;
          bfr[n] = *(const bf16x8*)&xs[(r*36 + c)*80 + ((lq ^ ((c>>3)&3)) << 4)];
        }
        #pragma unroll
        for (int m = 0; m < 4; ++m)
          #pragma unroll
          for (int n = 0; n < 4; ++n)
            acc[m][n] = __builtin_amdgcn_mfma_f32_16x16x32_bf16(af[m], bfr[n], acc[m][n], 0, 0, 0);
        #pragma unroll
        for (int m = 0; m < 4; ++m) af[m] = afn[m];
      }
    }
  }
  // ---- epilogue: D col = pixel (lane&15), row = oc ((lane>>4)*4 + j) ----
  #pragma unroll
  for (int n = 0; n < 4; ++n) {
    const int py = y0 + wn*2 + (n>>1);
    const int px = x0 + (n&1)*16 + l15;
    if (py < 258 && px < 258) {
      #pragma unroll
      for (int m = 0; m < 4; ++m) {
        const int oc0 = wm*64 + m*16 + lq*4;
        float* dst = conv_out + ((size_t)(b*128 + oc0)*258 + py)*258 + px;
        #pragma unroll
        for (int j = 0; j < 4; ++j)
          dst[(size_t)j*66564] = acc[m][n][j] + bias_lds[oc0 + j];
      }
    }
  }
}

// ---------------- fused up2x (sep) + lrelu/clamp + down2x (sep) ----------------
__global__ __launch_bounds__(256) void updown_kernel(
    const float* __restrict__ conv_out,
    const float* __restrict__ upf, const float* __restrict__ dnf,
    float* __restrict__ down2)
{
  __shared__ float Bp[26][266];   // up1 strip, 4-col zero pad each side (cols m+4)
  __shared__ float Dp[8][523];    // down1 strip (522 cols, +1 pad)
  const int strip = blockIdx.x, c = blockIdx.y, b = blockIdx.z;
  const int y0 = strip * 8;
  const int tid = threadIdx.x;
  float fu[12], fd[12];
  #pragma unroll
  for (int k = 0; k < 12; ++k) { fu[k] = upf[11-k] * 2.0f; fd[k] = dnf[11-k]; }
  if (tid < 208) { int r = tid >> 3, pc = tid & 7; int col = (pc < 4) ? pc : (258 + pc); Bp[r][col] = 0.f; }
  const float* src = conv_out + ((size_t)(b*128 + c)*258)*258;

  #pragma unroll 1
  for (int m = tid; m < 258; m += 256) {
    float a[18];
    #pragma unroll
    for (int r = 0; r < 18; ++r) {
      int gy = y0 - 4 + r;
      a[r] = ((unsigned)gy < 258u) ? src[gy*258 + m] : 0.f;
    }
    #pragma unroll
    for (int v = 0; v < 26; ++v) {
      const int k0 = (v & 1) ? 0 : 1;
      float sacc = 0.f;
      #pragma unroll
      for (int j = 0; j < 6; ++j) {
        const int rl = (v + k0 + 2*j - 9)/2 + 4;
        sacc += fu[k0 + 2*j] * a[rl];
      }
      Bp[v][m + 4] = sacc;
    }
  }
  __syncthreads();

  #pragma unroll 1
  for (int q = tid; q < 261; q += 256) {
    float dacc0[8], dacc1[8];
    #pragma unroll
    for (int t = 0; t < 8; ++t) { dacc0[t] = 0.f; dacc1[t] = 0.f; }
    #pragma unroll
    for (int v = 0; v < 26; ++v) {
      float w0 = Bp[v][q+0], w1 = Bp[v][q+1], w2 = Bp[v][q+2];
      float w3 = Bp[v][q+3], w4 = Bp[v][q+4], w5 = Bp[v][q+5];
      float c0 = fu[1]*w0 + fu[3]*w1 + fu[5]*w2 + fu[7]*w3 + fu[9]*w4 + fu[11]*w5;
      float c1 = fu[0]*w0 + fu[2]*w1 + fu[4]*w2 + fu[6]*w3 + fu[8]*w4 + fu[10]*w5;
      c0 = fminf(fmaxf((c0 < 0.f ? c0*0.2f : c0)*1.41421356237f, -256.f), 256.f);
      c1 = fminf(fmaxf((c1 < 0.f ? c1*0.2f : c1)*1.41421356237f, -256.f), 256.f);
      #pragma unroll
      for (int t = 0; t < 8; ++t) {
        const int k = v - 2*t;
        if (k >= 0 && k < 12) { dacc0[t] += fd[k]*c0; dacc1[t] += fd[k]*c1; }
      }
    }
    #pragma unroll
    for (int t = 0; t < 8; ++t) { Dp[t][2*q] = dacc0[t]; Dp[t][2*q+1] = dacc1[t]; }
  }
  __syncthreads();

  const int ty = tid >> 5, xg = tid & 31;
  float* dst = down2 + ((size_t)(b*128 + c)*256 + (y0 + ty))*256;
  #pragma unroll
  for (int i = 0; i < 8; ++i) {
    int xc = xg + 32*i;
    float acc = 0.f;
    #pragma unroll
    for (int k = 0; k < 12; ++k) acc += fd[k] * Dp[ty][2*xc + k];
    dst[xc] = acc;
  }
}

// ---------------- rgb ----------------
__global__ __launch_bounds__(256) void rgb_kernel(
    const float* __restrict__ down2, const float* __restrict__ coef,
    const float* __restrict__ brgb, float* __restrict__ yout)
{
  __shared__ float cl[3][128];
  const int b = blockIdx.x >> 8;
  const int p = ((blockIdx.x & 255) << 8) + threadIdx.x;
  for (int e = threadIdx.x; e < 384; e += 256) cl[e >> 7][e & 127] = coef[b*384 + e];
  __syncthreads();
  float a0 = 0.f, a1 = 0.f, a2 = 0.f;
  const float* dsrc = down2 + (size_t)b*128*65536 + p;
  #pragma unroll 4
  for (int i = 0; i < 128; ++i) {
    float v = dsrc[(size_t)i*65536];
    a0 += cl[0][i]*v; a1 += cl[1][i]*v; a2 += cl[2][i]*v;
  }
  const size_t ob = (size_t)b*3*65536 + p;
  yout[ob]          = fminf(fmaxf(a0 + brgb[0], -256.f), 256.f);
  yout[ob + 65536]  = fminf(fmaxf(a1 + brgb[1], -256.f), 256.f);
  yout[ob + 131072] = fminf(fmaxf(a2 + brgb[2], -256.f), 256.f);
}

extern "C" void kernel_launch(void* const* d_in, const int* in_sizes, int n_in,
                              void* d_out, int out_size, void* d_ws, size_t ws_size,
                              hipStream_t stream) {
  const float* x      = (const float*)d_in[0];
  const float* w      = (const float*)d_in[1];
  const float* afw    = (const float*)d_in[2];
  const float* afb    = (const float*)d_in[3];
  const float* wfeat  = (const float*)d_in[4];
  const float* bfeat  = (const float*)d_in[5];
  const float* argbw  = (const float*)d_in[6];
  const float* argbb  = (const float*)d_in[7];
  const float* wrgb   = (const float*)d_in[8];
  const float* brgb   = (const float*)d_in[9];
  const float* upf    = (const float*)d_in[10];
  const float* dnf    = (const float*)d_in[11];
  const float* emaf   = (const float*)d_in[12];
  const float* emar   = (const float*)d_in[13];

  float* ws = (float*)d_ws;
  size_t off = 0;
  float* s_feat   = ws + off; off += 256;
  float* wnscale  = ws + off; off += 128;
  float* coef     = ws + off; off += 768;
  short* wfrag    = (short*)(ws + off); off += 147456;          // 294912 bf16
  float* conv_out = ws + off; off += (size_t)2*128*258*258;     // 17,040,384
  float* down2    = ws + off; off += (size_t)2*128*256*256;     // 16,777,216
  if (ws_size < off * sizeof(float)) return;
  float* yout = (float*)d_out;

  prep1_kernel<<<1, 256, 0, stream>>>(w, afw, afb, argbw, argbb, wrgb, wfeat, emar,
                                      s_feat, wnscale, coef);
  prep2_kernel<<<256, 128, 0, stream>>>(wfeat, s_feat, wnscale, emaf, wfrag);
  conv_mfma_kernel<<<dim3(9, 65, 2), 256, 0, stream>>>(x, wfrag, bfeat, conv_out);
  updown_kernel<<<dim3(32, 128, 2), 256, 0, stream>>>(conv_out, upf, dnf, down2);
  rgb_kernel<<<512, 256, 0, stream>>>(down2, coef, brgb, yout);
}

// Round 3
// 307.744 us; speedup vs baseline: 7.0969x; 1.1018x over previous
//
#include <hip/hip_runtime.h>
#include <hip/hip_bf16.h>
#include <cstdint>

typedef __attribute__((ext_vector_type(8))) short bf16x8;
typedef __attribute__((ext_vector_type(4))) float f32x4;

__device__ inline uint16_t f2bf(float f) {
  uint32_t u = __float_as_uint(f);
  u += 0x7FFF + ((u >> 16) & 1);          // round-to-nearest-even
  return (uint16_t)(u >> 16);
}

// ---------------- prep1: s_feat (RMS-normalized), rgb coefs ----------------
// wave-cooperative dots: lanes over k (coalesced), shuffle reduce.
__global__ __launch_bounds__(256) void prep1_kernel(
    const float* __restrict__ w,        // (2,512)
    const float* __restrict__ afw,      // (128,512)
    const float* __restrict__ afb,      // (128)
    const float* __restrict__ argbw,    // (128,512)
    const float* __restrict__ argbb,    // (128)
    const float* __restrict__ wrgb,     // (3,128)
    const float* __restrict__ ema_r,    // (1)
    float* __restrict__ s_feat_out,     // (2,128)
    float* __restrict__ coef_out)       // (2,3,128)
{
  __shared__ float sfeat_s[256];
  __shared__ float srgb_s[256];
  __shared__ float sred[256];
  const int tid = threadIdx.x, lane = tid & 63, wv = tid >> 6;
  const float wg = 0.04419417382415922f;    // 1/sqrt(512)
  #pragma unroll 2
  for (int p = wv; p < 256; p += 4) {
    const int bb = p >> 7, c = p & 127;
    float d1 = 0.f, d2 = 0.f;
    #pragma unroll
    for (int it = 0; it < 8; ++it) {
      const int k = lane + 64*it;
      const float wvv = w[bb*512 + k];
      d1 += wvv * afw[c*512 + k];
      d2 += wvv * argbw[c*512 + k];
    }
    #pragma unroll
    for (int off = 32; off; off >>= 1) {
      d1 += __shfl_xor(d1, off, 64);
      d2 += __shfl_xor(d2, off, 64);
    }
    if (lane == 0) {
      sfeat_s[p] = d1 * wg + afb[c];
      srgb_s[p]  = (d2 * wg + argbb[c]) * 0.08838834764831845f * rsqrtf(ema_r[0]);
    }
  }
  __syncthreads();
  const float sf = sfeat_s[tid];
  sred[tid] = sf * sf;
  __syncthreads();
  for (int off = 128; off > 0; off >>= 1) {
    if (tid < off) sred[tid] += sred[tid + off];
    __syncthreads();
  }
  const float snorm = rsqrtf(sred[0] * (1.0f/256.0f));
  s_feat_out[tid] = sf * snorm;
  for (int e = tid; e < 768; e += 256) {
    int bb = e / 384, o = (e % 384) / 128, i = e & 127;
    coef_out[e] = wrgb[o*128 + i] * srgb_s[bb*128 + i];
  }
}

// ---------------- prep2: wnscale (inline) + modulate + demod -> bf16 A-fragments ----------------
// wfrag layout: [b][kidx 0..35][mglob 0..7][lane 0..63][j 0..7]  (short/bf16)
__global__ __launch_bounds__(128) void prep2_kernel(
    const float* __restrict__ wfeat, const float* __restrict__ s_feat,
    const float* __restrict__ ema_f, short* __restrict__ wfrag)
{
  __shared__ float red[128];
  const int bo = blockIdx.x, b = bo >> 7, o = bo & 127;
  const int i = threadIdx.x;
  float wraw[9]; float ssr = 0.f;
  #pragma unroll
  for (int j = 0; j < 9; ++j) { wraw[j] = wfeat[(o*128 + i)*9 + j]; ssr += wraw[j]*wraw[j]; }
  red[i] = ssr; __syncthreads();
  for (int off = 64; off > 0; off >>= 1) { if (i < off) red[i] += red[i+off]; __syncthreads(); }
  const float wsc = rsqrtf(red[0] * (1.0f/1152.0f));
  const float sv = s_feat[b*128 + i];
  float wr[9]; float ss = 0.f;
  #pragma unroll
  for (int j = 0; j < 9; ++j) { wr[j] = wraw[j] * wsc * sv; ss += wr[j]*wr[j]; }
  __syncthreads();
  red[i] = ss; __syncthreads();
  for (int off = 64; off > 0; off >>= 1) { if (i < off) red[i] += red[i+off]; __syncthreads(); }
  const float d = rsqrtf(red[0] + 1e-8f) * rsqrtf(ema_f[0]);
  const int chunk = i >> 5;
  const int lane = (o & 15) | (((i >> 3) & 3) << 4);
  const int jj = i & 7;
  #pragma unroll
  for (int tap = 0; tap < 9; ++tap) {
    int kidx = chunk*9 + tap;
    size_t sidx = ((((size_t)b*36 + kidx)*8 + (o >> 4)) << 9) + (lane << 3) + jj;
    wfrag[sidx] = (short)f2bf(wr[tap] * d);
  }
}

// ---------------- conv via bf16 MFMA implicit GEMM, double-buffered + issue-early staging ----------------
// block: 128 oc x (4 rows x 32 cols); 4 waves 2x2; wave: 64 oc x 64 px
__global__ __launch_bounds__(256, 3) void conv_mfma_kernel(
    const float* __restrict__ x, const short* __restrict__ wfrag,
    const float* __restrict__ bias_feat, float* __restrict__ conv_out)
{
  __shared__ char xs[2][17280];
  __shared__ float bias_lds[128];
  const int tid = threadIdx.x;
  const int bx = blockIdx.x, by = blockIdx.y, b = blockIdx.z;
  const int x0 = bx * 32, y0 = by * 4;
  const int lane = tid & 63, wave = tid >> 6;
  const int wm = wave >> 1, wn = wave & 1;
  const int l15 = lane & 15, lq = lane >> 4;
  if (tid < 128) bias_lds[tid] = bias_feat[tid];

  f32x4 acc[4][4] = {};

  const int pr = tid >> 5, cw = tid & 31;
  const int gx = x0 - 2 + cw;
  const bool xok = (unsigned)gx < 256u;
  // edge cols 32,33 of tile: flat map, threads 0..191 -> (ic 0..31, r 0..5)
  const bool eact = tid < 192;
  const int eic = tid & 31, er = tid >> 5;
  const int egy = y0 - 2 + er;
  const int egx = x0 + 30;
  const bool e0ok = eact && ((unsigned)egy < 256u) && (egx < 256);
  const bool e1ok = eact && ((unsigned)egy < 256u) && (egx + 1 < 256);

  const short* wbase = wfrag + (((size_t)b*36*8) + (size_t)wm*4) * 512 + (size_t)lane * 8;

  float st[2][6][2]; float ef[2];

  auto STAGE_LOAD = [&](int ch) {
    #pragma unroll
    for (int s = 0; s < 2; ++s) {
      const int ic = ch*32 + 2*(pr + 8*s);
      const float* s0 = x + ((size_t)(b*128 + ic)) * 65536;
      #pragma unroll
      for (int r = 0; r < 6; ++r) {
        const int gy = y0 - 2 + r;
        const bool ok = xok && ((unsigned)gy < 256u);
        st[s][r][0] = ok ? s0[gy*256 + gx] : 0.f;
        st[s][r][1] = ok ? s0[65536 + gy*256 + gx] : 0.f;
      }
    }
    const size_t ebase = ((size_t)(b*128 + ch*32 + eic))*65536 + (size_t)egy*256 + egx;
    ef[0] = e0ok ? x[ebase]     : 0.f;
    ef[1] = e1ok ? x[ebase + 1] : 0.f;
  };

  auto STAGE_WRITE = [&](int buf) {
    char* base = xs[buf];
    #pragma unroll
    for (int s = 0; s < 2; ++s) {
      const int pp = pr + 8*s;
      const int sw = (((pp>>2) ^ ((cw>>3)&3)) << 4) + ((pp&3) << 2);
      #pragma unroll
      for (int r = 0; r < 6; ++r) {
        uint32_t pk = ((uint32_t)f2bf(st[s][r][1]) << 16) | f2bf(st[s][r][0]);
        *(uint32_t*)&base[(r*36 + cw)*80 + sw] = pk;
      }
    }
    if (eact) {
      const int pp = eic >> 1, half = eic & 1;
      #pragma unroll
      for (int j = 0; j < 2; ++j) {
        const int c2 = 32 + j;
        const int swz = ((pp>>2) << 4) + ((pp&3) << 2) + half*2;   // (c2>>3)&3 == 0
        *(uint16_t*)&base[(er*36 + c2)*80 + swz] = f2bf(ef[j]);
      }
    }
  };

  auto COMPUTE = [&](int buf, int ch) {
    const char* base = xs[buf];
    #pragma unroll
    for (int ky = 0; ky < 3; ++ky) {
      #pragma unroll
      for (int kx = 0; kx < 3; ++kx) {
        const int kidx = ch*9 + ky*3 + kx;
        const short* wp = wbase + (size_t)kidx * 4096;
        bf16x8 a_[4];
        #pragma unroll
        for (int m = 0; m < 4; ++m) a_[m] = *(const bf16x8*)(wp + m*512);
        bf16x8 bfr[4];
        #pragma unroll
        for (int n = 0; n < 4; ++n) {
          const int r = wn*2 + (n>>1) + ky;
          const int c = (n&1)*16 + l15 + kx;
          bfr[n] = *(const bf16x8*)&base[(r*36 + c)*80 + ((lq ^ ((c>>3)&3)) << 4)];
        }
        #pragma unroll
        for (int m = 0; m < 4; ++m)
          #pragma unroll
          for (int n = 0; n < 4; ++n)
            acc[m][n] = __builtin_amdgcn_mfma_f32_16x16x32_bf16(a_[m], bfr[n], acc[m][n], 0, 0, 0);
      }
    }
  };

  STAGE_LOAD(0);
  STAGE_WRITE(0);
  __syncthreads();
  #pragma unroll 2
  for (int ch = 0; ch < 4; ++ch) {
    if (ch < 3) STAGE_LOAD(ch + 1);        // issue early: hides under MFMAs
    COMPUTE(ch & 1, ch);
    if (ch < 3) { STAGE_WRITE((ch + 1) & 1); __syncthreads(); }
  }

  // epilogue: D col = pixel (lane&15), row = oc ((lane>>4)*4 + j)
  #pragma unroll
  for (int n = 0; n < 4; ++n) {
    const int py = y0 + wn*2 + (n>>1);
    const int px = x0 + (n&1)*16 + l15;
    if (py < 258 && px < 258) {
      #pragma unroll
      for (int m = 0; m < 4; ++m) {
        const int oc0 = wm*64 + m*16 + lq*4;
        float* dst = conv_out + ((size_t)(b*128 + oc0)*258 + py)*258 + px;
        #pragma unroll
        for (int j = 0; j < 4; ++j)
          dst[(size_t)j*66564] = acc[m][n][j] + bias_lds[oc0 + j];
      }
    }
  }
}

// ---------------- fused up2x (sep) + lrelu/clamp + down2x (sep) ----------------
__global__ __launch_bounds__(256) void updown_kernel(
    const float* __restrict__ conv_out,
    const float* __restrict__ upf, const float* __restrict__ dnf,
    float* __restrict__ down2)
{
  __shared__ float Bp[26][266];   // up1 strip, 4-col zero pad each side (cols m+4)
  __shared__ float Dp[8][523];    // down1 strip (522 cols, +1 pad)
  const int strip = blockIdx.x, c = blockIdx.y, b = blockIdx.z;
  const int y0 = strip * 8;
  const int tid = threadIdx.x;
  float fu[12], fd[12];
  #pragma unroll
  for (int k = 0; k < 12; ++k) { fu[k] = upf[11-k] * 2.0f; fd[k] = dnf[11-k]; }
  if (tid < 208) { int r = tid >> 3, pc = tid & 7; int col = (pc < 4) ? pc : (258 + pc); Bp[r][col] = 0.f; }
  const float* src = conv_out + ((size_t)(b*128 + c)*258)*258;

  // P1: vertical upsample, global -> LDS (threads over columns m)
  #pragma unroll 1
  for (int m = tid; m < 258; m += 256) {
    float a[18];
    #pragma unroll
    for (int r = 0; r < 18; ++r) {
      int gy = y0 - 4 + r;
      a[r] = ((unsigned)gy < 258u) ? src[gy*258 + m] : 0.f;
    }
    #pragma unroll
    for (int v = 0; v < 26; ++v) {
      const int k0 = (v & 1) ? 0 : 1;
      float sacc = 0.f;
      #pragma unroll
      for (int j = 0; j < 6; ++j) {
        const int rl = (v + k0 + 2*j - 9)/2 + 4;
        sacc += fu[k0 + 2*j] * a[rl];
      }
      Bp[v][m + 4] = sacc;
    }
  }
  __syncthreads();

  // P2: horizontal upsample + lrelu + vertical downsample (unpredicated)
  #pragma unroll 1
  for (int q = tid; q < 261; q += 256) {
    float cc0[26], cc1[26];
    #pragma unroll
    for (int v = 0; v < 26; ++v) {
      float w0 = Bp[v][q+0], w1 = Bp[v][q+1], w2 = Bp[v][q+2];
      float w3 = Bp[v][q+3], w4 = Bp[v][q+4], w5 = Bp[v][q+5];
      float c0 = fu[1]*w0 + fu[3]*w1 + fu[5]*w2 + fu[7]*w3 + fu[9]*w4 + fu[11]*w5;
      float c1 = fu[0]*w0 + fu[2]*w1 + fu[4]*w2 + fu[6]*w3 + fu[8]*w4 + fu[10]*w5;
      cc0[v] = fminf(fmaxf((c0 < 0.f ? c0*0.2f : c0)*1.41421356237f, -256.f), 256.f);
      cc1[v] = fminf(fmaxf((c1 < 0.f ? c1*0.2f : c1)*1.41421356237f, -256.f), 256.f);
    }
    #pragma unroll
    for (int t = 0; t < 8; ++t) {
      float a0 = 0.f, a1 = 0.f;
      #pragma unroll
      for (int k = 0; k < 12; ++k) {
        a0 += fd[k]*cc0[2*t + k];
        a1 += fd[k]*cc1[2*t + k];
      }
      Dp[t][2*q] = a0; Dp[t][2*q+1] = a1;
    }
  }
  __syncthreads();

  // P3: horizontal downsample, LDS -> global
  const int ty = tid >> 5, xg = tid & 31;
  float* dst = down2 + ((size_t)(b*128 + c)*256 + (y0 + ty))*256;
  #pragma unroll
  for (int i = 0; i < 8; ++i) {
    int xc = xg + 32*i;
    float acc = 0.f;
    #pragma unroll
    for (int k = 0; k < 12; ++k) acc += fd[k] * Dp[ty][2*xc + k];
    dst[xc] = acc;
  }
}

// ---------------- rgb ----------------
__global__ __launch_bounds__(256) void rgb_kernel(
    const float* __restrict__ down2, const float* __restrict__ coef,
    const float* __restrict__ brgb, float* __restrict__ yout)
{
  __shared__ float cl[3][128];
  const int b = blockIdx.x >> 8;
  const int p = ((blockIdx.x & 255) << 8) + threadIdx.x;
  for (int e = threadIdx.x; e < 384; e += 256) cl[e >> 7][e & 127] = coef[b*384 + e];
  __syncthreads();
  float a0 = 0.f, a1 = 0.f, a2 = 0.f;
  const float* dsrc = down2 + (size_t)b*128*65536 + p;
  #pragma unroll 4
  for (int i = 0; i < 128; ++i) {
    float v = dsrc[(size_t)i*65536];
    a0 += cl[0][i]*v; a1 += cl[1][i]*v; a2 += cl[2][i]*v;
  }
  const size_t ob = (size_t)b*3*65536 + p;
  yout[ob]          = fminf(fmaxf(a0 + brgb[0], -256.f), 256.f);
  yout[ob + 65536]  = fminf(fmaxf(a1 + brgb[1], -256.f), 256.f);
  yout[ob + 131072] = fminf(fmaxf(a2 + brgb[2], -256.f), 256.f);
}

extern "C" void kernel_launch(void* const* d_in, const int* in_sizes, int n_in,
                              void* d_out, int out_size, void* d_ws, size_t ws_size,
                              hipStream_t stream) {
  const float* x      = (const float*)d_in[0];
  const float* w      = (const float*)d_in[1];
  const float* afw    = (const float*)d_in[2];
  const float* afb    = (const float*)d_in[3];
  const float* wfeat  = (const float*)d_in[4];
  const float* bfeat  = (const float*)d_in[5];
  const float* argbw  = (const float*)d_in[6];
  const float* argbb  = (const float*)d_in[7];
  const float* wrgb   = (const float*)d_in[8];
  const float* brgb   = (const float*)d_in[9];
  const float* upf    = (const float*)d_in[10];
  const float* dnf    = (const float*)d_in[11];
  const float* emaf   = (const float*)d_in[12];
  const float* emar   = (const float*)d_in[13];

  float* ws = (float*)d_ws;
  size_t off = 0;
  float* s_feat   = ws + off; off += 256;
  float* coef     = ws + off; off += 768;
  short* wfrag    = (short*)(ws + off); off += 147456;          // 294912 bf16
  float* conv_out = ws + off; off += (size_t)2*128*258*258;     // 17,040,384
  float* down2    = ws + off; off += (size_t)2*128*256*256;     // 16,777,216
  if (ws_size < off * sizeof(float)) return;
  float* yout = (float*)d_out;

  prep1_kernel<<<1, 256, 0, stream>>>(w, afw, afb, argbw, argbb, wrgb, emar,
                                      s_feat, coef);
  prep2_kernel<<<256, 128, 0, stream>>>(wfeat, s_feat, emaf, wfrag);
  conv_mfma_kernel<<<dim3(9, 65, 2), 256, 0, stream>>>(x, wfrag, bfeat, conv_out);
  updown_kernel<<<dim3(32, 128, 2), 256, 0, stream>>>(conv_out, upf, dnf, down2);
  rgb_kernel<<<512, 256, 0, stream>>>(down2, coef, brgb, yout);
}